// Round 1
// 911.642 us; speedup vs baseline: 1.0166x; 1.0166x over previous
//
#include <hip/hip_runtime.h>

// SpMM via two-level counting sort + deterministic gather.
//  1. coarse_count:   196-bucket histogram (row>>10), LDS-privatized
//  2. scan_buckets:   1-block scan -> bucket_base/cursor; offsets[N]=nnz
//  3. coarse_scatter: LDS multisplit per 8192-edge tile -> bucket-grouped
//                     (packed,val) pairs, coalesced ~336B runs
//  4. fine_permute:   one block per bucket; LDS 1024-row hist+scan; scatter
//                     confined to 262KB region (single CU -> L2-local line
//                     assembly); also writes CSR offsets
//  5. gather_k:       one wave per row; readlane broadcast (no bpermute),
//                     8x-unrolled independent gathers, nt loads/stores so
//                     ego stays L3-resident

constexpr int D = 128;
constexpr int NB = 196;        // buckets of 1024 rows (200000 -> 196)
constexpr int TILE = 8192;
constexpr int THREADS = 256;

__global__ void __launch_bounds__(256)
coarse_count(const int* __restrict__ rows, int* __restrict__ bcnt, int nnz) {
    __shared__ int h[256];
    int tid = threadIdx.x;
    h[tid] = 0;
    __syncthreads();
    int base = blockIdx.x * TILE;
    int cnt = min(TILE, nnz - base);
    for (int i = tid; i < cnt; i += THREADS)
        atomicAdd(&h[rows[base + i] >> 10], 1);
    __syncthreads();
    if (h[tid]) atomicAdd(&bcnt[tid], h[tid]);
}

__global__ void __launch_bounds__(256)
scan_buckets(const int* __restrict__ bcnt, int* __restrict__ bbase,
             int* __restrict__ bcursor, int* __restrict__ offsets, int N, int nnz) {
    __shared__ int s[256];
    int tid = threadIdx.x;
    int v = (tid < NB) ? bcnt[tid] : 0;
    s[tid] = v;
    __syncthreads();
    for (int off = 1; off < 256; off <<= 1) {
        int t = (tid >= off) ? s[tid - off] : 0;
        __syncthreads();
        s[tid] += t;
        __syncthreads();
    }
    int ex = s[tid] - v;  // exclusive
    if (tid <= NB) bbase[tid] = ex;          // bbase[NB] = nnz
    if (tid < NB)  bcursor[tid] = ex;
    if (tid == 0)  offsets[N] = nnz;
}

__global__ void __launch_bounds__(256)
coarse_scatter(const int* __restrict__ rows, const int* __restrict__ cols,
               const float* __restrict__ vals, int* __restrict__ bcursor,
               int2* __restrict__ pairs, int nnz) {
    __shared__ int h[256], sc[256], cur[256], gb[256];
    __shared__ unsigned short src[TILE];
    int tid = threadIdx.x;
    h[tid] = 0;
    __syncthreads();
    int base = blockIdx.x * TILE;
    int cnt = min(TILE, nnz - base);
    for (int i = tid; i < cnt; i += THREADS)
        atomicAdd(&h[rows[base + i] >> 10], 1);
    __syncthreads();
    int v = h[tid];
    sc[tid] = v;
    __syncthreads();
    for (int off = 1; off < 256; off <<= 1) {
        int t = (tid >= off) ? sc[tid - off] : 0;
        __syncthreads();
        sc[tid] += t;
        __syncthreads();
    }
    int excl = sc[tid] - v;
    cur[tid] = excl;
    if (v) gb[tid] = atomicAdd(&bcursor[tid], v) - excl;  // gdst = gb[b] + slot
    __syncthreads();
    // place tile-local indices into bucket-sorted LDS order
    for (int i = tid; i < cnt; i += THREADS) {
        int b = rows[base + i] >> 10;
        int slot = atomicAdd(&cur[b], 1);
        src[slot] = (unsigned short)i;
    }
    __syncthreads();
    // emit bucket-grouped pairs: consecutive slots -> consecutive gdst
    for (int s_ = tid; s_ < cnt; s_ += THREADS) {
        int e = src[s_];
        int r = rows[base + e];
        int c = cols[base + e];
        float vv = vals[base + e];
        pairs[gb[r >> 10] + s_] = make_int2(((r & 1023) << 18) | c, __float_as_int(vv));
    }
}

__global__ void __launch_bounds__(1024)
fine_permute(const int* __restrict__ bbase, const int2* __restrict__ pairs,
             int2* __restrict__ fpairs, int* __restrict__ offsets, int N) {
    __shared__ int h[1024], s[1024], cur[1024];
    int b = blockIdx.x, tid = threadIdx.x;
    int base = bbase[b], end = bbase[b + 1], cnt = end - base;
    h[tid] = 0;
    __syncthreads();
    for (int i = tid; i < cnt; i += 1024)
        atomicAdd(&h[pairs[base + i].x >> 18], 1);
    __syncthreads();
    int v = h[tid];
    s[tid] = v;
    __syncthreads();
    for (int off = 1; off < 1024; off <<= 1) {
        int t = (tid >= off) ? s[tid - off] : 0;
        __syncthreads();
        s[tid] += t;
        __syncthreads();
    }
    int excl = s[tid] - v;
    cur[tid] = excl;
    int rg = (b << 10) + tid;
    if (rg < N) offsets[rg] = base + excl;   // CSR offsets for free
    __syncthreads();
    for (int i = tid; i < cnt; i += 1024) {
        int2 p = pairs[base + i];
        int pos = atomicAdd(&cur[p.x >> 18], 1);
        fpairs[base + pos] = p;   // 262KB window, single CU -> L2-local
    }
}

__global__ void __launch_bounds__(256)
gather_k(const int* __restrict__ offsets, const int2* __restrict__ pairs,
         const float* __restrict__ ego, float* __restrict__ out, int n) {
    int wid  = (blockIdx.x * blockDim.x + threadIdx.x) >> 6;
    int lane = threadIdx.x & 63;
    if (wid >= n) return;
    int start = offsets[wid];
    int end   = offsets[wid + 1];
    float2 acc = {0.f, 0.f};
    for (int bb = start; bb < end; bb += 64) {
        int j = bb + lane;
        int cvx = 0, cvy = 0;
        if (j < end) {
            unsigned long long p =
                __builtin_nontemporal_load((const unsigned long long*)(pairs + j));
            cvx = (int)(unsigned)(p & 0xFFFFFFFFull);
            cvy = (int)(unsigned)(p >> 32);
        }
        int m_ = min(64, end - bb);
        int k = 0;
        // 8x unrolled: broadcast via readlane (k is wave-uniform -> SGPR,
        // no ds_bpermute in the chain; ego base is scalar), then 8
        // independent 512B wave-gathers in flight before the FMAs.
        for (; k + 8 <= m_; k += 8) {
            int c0 = __builtin_amdgcn_readlane(cvx, k + 0) & 0x3FFFF;
            int c1 = __builtin_amdgcn_readlane(cvx, k + 1) & 0x3FFFF;
            int c2 = __builtin_amdgcn_readlane(cvx, k + 2) & 0x3FFFF;
            int c3 = __builtin_amdgcn_readlane(cvx, k + 3) & 0x3FFFF;
            int c4 = __builtin_amdgcn_readlane(cvx, k + 4) & 0x3FFFF;
            int c5 = __builtin_amdgcn_readlane(cvx, k + 5) & 0x3FFFF;
            int c6 = __builtin_amdgcn_readlane(cvx, k + 6) & 0x3FFFF;
            int c7 = __builtin_amdgcn_readlane(cvx, k + 7) & 0x3FFFF;
            float v0 = __int_as_float(__builtin_amdgcn_readlane(cvy, k + 0));
            float v1 = __int_as_float(__builtin_amdgcn_readlane(cvy, k + 1));
            float v2 = __int_as_float(__builtin_amdgcn_readlane(cvy, k + 2));
            float v3 = __int_as_float(__builtin_amdgcn_readlane(cvy, k + 3));
            float v4 = __int_as_float(__builtin_amdgcn_readlane(cvy, k + 4));
            float v5 = __int_as_float(__builtin_amdgcn_readlane(cvy, k + 5));
            float v6 = __int_as_float(__builtin_amdgcn_readlane(cvy, k + 6));
            float v7 = __int_as_float(__builtin_amdgcn_readlane(cvy, k + 7));
            float2 e0 = ((const float2*)(ego + (size_t)c0 * D))[lane];
            float2 e1 = ((const float2*)(ego + (size_t)c1 * D))[lane];
            float2 e2 = ((const float2*)(ego + (size_t)c2 * D))[lane];
            float2 e3 = ((const float2*)(ego + (size_t)c3 * D))[lane];
            float2 e4 = ((const float2*)(ego + (size_t)c4 * D))[lane];
            float2 e5 = ((const float2*)(ego + (size_t)c5 * D))[lane];
            float2 e6 = ((const float2*)(ego + (size_t)c6 * D))[lane];
            float2 e7 = ((const float2*)(ego + (size_t)c7 * D))[lane];
            acc.x += v0 * e0.x; acc.y += v0 * e0.y;
            acc.x += v1 * e1.x; acc.y += v1 * e1.y;
            acc.x += v2 * e2.x; acc.y += v2 * e2.y;
            acc.x += v3 * e3.x; acc.y += v3 * e3.y;
            acc.x += v4 * e4.x; acc.y += v4 * e4.y;
            acc.x += v5 * e5.x; acc.y += v5 * e5.y;
            acc.x += v6 * e6.x; acc.y += v6 * e6.y;
            acc.x += v7 * e7.x; acc.y += v7 * e7.y;
        }
        for (; k < m_; ++k) {
            int   c = __builtin_amdgcn_readlane(cvx, k) & 0x3FFFF;
            float v = __int_as_float(__builtin_amdgcn_readlane(cvy, k));
            float2 e = ((const float2*)(ego + (size_t)c * D))[lane];
            acc.x += v * e.x;
            acc.y += v * e.y;
        }
    }
    unsigned long long bits;
    __builtin_memcpy(&bits, &acc, 8);
    __builtin_nontemporal_store(bits,
        (unsigned long long*)(out + (size_t)wid * D + 2 * lane));
}

// insurance fallback (round-1 atomic scatter) if ws is too small
__global__ void __launch_bounds__(256)
spmm_scatter(const float* __restrict__ vals, const int* __restrict__ rows,
             const int* __restrict__ cols, const float* __restrict__ ego,
             float* __restrict__ out, int nnz) {
    int edge = (blockIdx.x * blockDim.x + threadIdx.x) >> 6;
    int lane = threadIdx.x & 63;
    if (edge >= nnz) return;
    int   r = __builtin_amdgcn_readfirstlane(rows[edge]);
    int   c = __builtin_amdgcn_readfirstlane(cols[edge]);
    float v = vals[edge];
    float2 m = ((const float2*)(ego + (size_t)c * D))[lane];
    float* dst = out + (size_t)r * D + 2 * lane;
    unsafeAtomicAdd(dst,     v * m.x);
    unsafeAtomicAdd(dst + 1, v * m.y);
}

extern "C" void kernel_launch(void* const* d_in, const int* in_sizes, int n_in,
                              void* d_out, int out_size, void* d_ws, size_t ws_size,
                              hipStream_t stream) {
    const float* ego  = (const float*)d_in[0];
    const float* vals = (const float*)d_in[1];
    const int*   rows = (const int*)d_in[2];
    const int*   cols = (const int*)d_in[3];
    float*       out  = (float*)d_out;
    int nnz = in_sizes[1];
    int N   = out_size / D;  // 200000

    size_t need = (size_t)(1024 + 200704) * 4 + (size_t)nnz * 16;
    if (ws_size < need) {
        hipMemsetAsync(d_out, 0, (size_t)out_size * sizeof(float), stream);
        spmm_scatter<<<(nnz + 3) / 4, 256, 0, stream>>>(vals, rows, cols, ego, out, nnz);
        return;
    }

    int* ws       = (int*)d_ws;
    int* bcnt     = ws;            // 256
    int* bbase    = ws + 256;      // 257 (pad 256)
    int* bcursor  = ws + 512;      // 256
    int* offsets  = ws + 1024;     // N+1, pad to 200704
    int2* pairs   = (int2*)(ws + 201728);
    int2* fpairs  = pairs + nnz;

    int ntiles = (nnz + TILE - 1) / TILE;  // 782

    hipMemsetAsync(bcnt, 0, 256 * sizeof(int), stream);
    coarse_count  <<<ntiles, 256, 0, stream>>>(rows, bcnt, nnz);
    scan_buckets  <<<1, 256, 0, stream>>>(bcnt, bbase, bcursor, offsets, N, nnz);
    coarse_scatter<<<ntiles, 256, 0, stream>>>(rows, cols, vals, bcursor, pairs, nnz);
    fine_permute  <<<NB, 1024, 0, stream>>>(bbase, pairs, fpairs, offsets, N);
    gather_k      <<<(N + 3) / 4, 256, 0, stream>>>(offsets, fpairs, ego, out, N);
}